// Round 1
// baseline (151.977 us; speedup 1.0000x reference)
//
#include <hip/hip_runtime.h>

#define IN_C 256
#define HID_C 256
#define OUT_C 64

#define NBK 64           // edge slices (= hist blocks)
#define NPAD 50176       // nodes padded to 196*256
#define N2 (NPAD / 2)    // packed u32 histogram entries (25088 -> 100352 B LDS)
#define NCH (NPAD / 256) // 196 chunks

typedef __attribute__((ext_vector_type(8))) short bf16x8;
typedef __attribute__((ext_vector_type(4))) float f32x4;
typedef __attribute__((ext_vector_type(2))) float f32x2;
typedef __attribute__((ext_vector_type(8))) unsigned short ushortx8;
typedef __attribute__((ext_vector_type(4))) unsigned int u32x4;
typedef __attribute__((ext_vector_type(2))) unsigned int u32x2;

__device__ inline float b2f(unsigned short u) {
    union { unsigned int u; float f; } v; v.u = ((unsigned int)u) << 16; return v.f;
}
__device__ inline unsigned short f2b(float f) {
    union { float f; unsigned int u; } v; v.f = f;
    unsigned int u = v.u;
    unsigned int r = (u + 0x7fffu + ((u >> 16) & 1u)) >> 16;  // RNE, no NaN expected
    return (unsigned short)r;
}

// fp8 (OCP e4m3) encode/decode via gfx950 HW converts
__device__ __forceinline__ unsigned char f2fp8(float v) {
    int pk = __builtin_amdgcn_cvt_pk_fp8_f32(v, v, 0, false);
    return (unsigned char)(pk & 0xff);
}
__device__ __forceinline__ void fp8acc4(unsigned int w, float& a0, float& a1, float& a2, float& a3) {
    f32x2 lo = __builtin_amdgcn_cvt_pk_f32_fp8((int)w, false);
    f32x2 hi = __builtin_amdgcn_cvt_pk_f32_fp8((int)w, true);
    a0 += lo.x; a1 += lo.y; a2 += hi.x; a3 += hi.y;
}

__device__ __forceinline__ void gl2lds16(const ushort* g, ushort* l) {
    __builtin_amdgcn_global_load_lds((const __attribute__((address_space(1))) void*)g,
                                     (__attribute__((address_space(3))) void*)l, 16, 0, 0);
}

__device__ __forceinline__ void conv8(const float* __restrict__ src, ushort* __restrict__ dst, int u) {
    const float4* p = (const float4*)(src + (size_t)u * 8);
    float4 a = p[0], b = p[1];
    ushort4 o0 = make_ushort4(f2b(a.x), f2b(a.y), f2b(a.z), f2b(a.w));
    ushort4 o1 = make_ushort4(f2b(b.x), f2b(b.y), f2b(b.z), f2b(b.w));
    ((ushort4*)(dst + (size_t)u * 8))[0] = o0;
    ((ushort4*)(dst + (size_t)u * 8))[1] = o1;
}

// ---------------- K1: full-N LDS-histogram degree+rank (disjoint slices) || conversions --------

__global__ __launch_bounds__(1024) void k_front(const int* __restrict__ dst, int E, int EPB,
                                                ushort* __restrict__ rank,
                                                unsigned int* __restrict__ cnt32,
                                                int* __restrict__ chunkpart,
                                                const float* __restrict__ x, ushort* __restrict__ xb,
                                                int xUnits,
                                                const float* __restrict__ Wl1, const float* __restrict__ Wr1,
                                                const float* __restrict__ Wl2, const float* __restrict__ Wr2,
                                                ushort* __restrict__ Wc1, ushort* __restrict__ Wc2) {
    const int bid = blockIdx.x;
    const int t = threadIdx.x;

    if (bid < NBK) {
        __shared__ unsigned int h[N2];  // 100352 B
        for (int i = t; i < N2; i += 1024) h[i] = 0;
        __syncthreads();

        const int e0 = bid * EPB;
        const int e1 = min(e0 + EPB, E);
        for (int e = e0 + t; e < e1; e += 1024) {
            int d = dst[e];
            int sh = (d & 1) << 4;
            unsigned int old = atomicAdd(&h[d >> 1], 1u << sh);
            rank[e] = (ushort)((old >> sh) & 0xffffu);
        }
        __syncthreads();

        unsigned int* outp = cnt32 + (size_t)bid * N2;
        for (int i = t; i < N2; i += 1024) outp[i] = h[i];

        if (t < NCH) {
            int c = t;
            int sum = 0;
#pragma unroll 8
            for (int j = 0; j < 128; ++j) {
                unsigned int v = h[c * 128 + ((j + c) & 127)];
                sum += (int)(v & 0xffffu) + (int)(v >> 16);
            }
            chunkpart[c * NBK + bid] = sum;
        }
        return;
    }

    const int ct = (bid - NBK) * 1024 + t;
    const int cn = 256 * 1024;
    for (int i = ct; i < 20480; i += cn) {
        if (i < 8192)       conv8(Wl1, Wc1,         i);
        else if (i < 16384) conv8(Wr1, Wc1 + 65536, i - 8192);
        else if (i < 18432) conv8(Wl2, Wc2,         i - 16384);
        else                conv8(Wr2, Wc2 + 16384, i - 18432);
    }
    for (int u = ct; u < xUnits; u += cn) conv8(x, xb, u);
}

// ---------------- K2: CSR scan; emits row_start + per-node per-slice offsets off16 ----------

__global__ __launch_bounds__(256) void k_scan(const unsigned int* __restrict__ cnt32,
                                              const int* __restrict__ chunkpart, int N,
                                              int* __restrict__ row_start,
                                              ushort* __restrict__ off16) {
    __shared__ int s[256];
    const int bid = blockIdx.x;
    const int t = threadIdx.x;

    int pre = 0;
    const int limit = bid * NBK;
    for (int i = t; i < limit; i += 256) pre += chunkpart[i];
    s[t] = pre;
    __syncthreads();
    for (int o = 128; o > 0; o >>= 1) {
        if (t < o) s[t] += s[t + o];
        __syncthreads();
    }
    const int chunk_off = s[0];
    __syncthreads();

    const int i = bid * 256 + t;
    const ushort* cnt16 = (const ushort*)cnt32;
    int run = 0;
#pragma unroll 8
    for (int b = 0; b < NBK; ++b) {
        ushort cv = cnt16[(size_t)b * NPAD + i];
        off16[(size_t)b * NPAD + i] = (ushort)run;
        run += cv;
    }
    int deg = run;

    s[t] = deg;
    __syncthreads();
    for (int o = 1; o < 256; o <<= 1) {
        int xx = (t >= o) ? s[t - o] : 0;
        __syncthreads();
        s[t] += xx;
        __syncthreads();
    }
    if (i < N) row_start[i + 1] = s[t] + chunk_off;
    if (i == 0) row_start[0] = 0;
}

// ---------------- MFMA GEMM + fused atomic-free scatter --------
// R17 change 1: double-buffered LDS (2x32KB), T3-minimum 2-phase pipeline:
//   prologue stage slab0 -> loop { stage slab t+1 ; ds_read+MFMA slab t ; barrier }
// One barrier per k-step (vs 2); the __syncthreads() vmcnt(0) drain now sits
// AFTER the MFMA phase, so the K=256 4-step loop no longer serializes a full
// HBM round-trip per step. LDS 64KB -> 2 blocks/CU (measured residency was
// only ~1.4 anyway; latency per block drops ~3-4x).
// Grid decode: by-fastest (same-bx blocks consecutive) + FULL m204 bijective XCD
// swizzle with remainder handling (nwg = 1564 / 391 are NOT multiples of 8).
// LDS layout stays LINEAR (R14-verified lane mapping, unchanged).

__global__ __launch_bounds__(256) void k_gemm_mfma(const ushort* __restrict__ A,
                                                   const ushort* __restrict__ W,
                                                   unsigned char* __restrict__ Cp,
                                                   ushort* __restrict__ Cr,
                                                   int N, int K, int PC, int nby, int nwg,
                                                   int nScat,
                                                   const int* __restrict__ src, const int* __restrict__ dst,
                                                   const ushort* __restrict__ rank,
                                                   const int* __restrict__ row_start,
                                                   const ushort* __restrict__ off16,
                                                   int E, int EPB, int* __restrict__ eidx) {
    if (blockIdx.x < (unsigned)nScat) {
        int base = blockIdx.x * 256 + threadIdx.x;
        int stride = nScat * 256;
        for (int e = base; e < E; e += stride) {
            int d = dst[e];
            int b = e / EPB;
            eidx[row_start[d] + (int)off16[(size_t)b * NPAD + d] + (int)rank[e]] = src[e];
        }
        return;
    }

    __shared__ ushort As[2][128 * 64];
    __shared__ ushort Bs[2][128 * 64];

    // full m204 bijective XCD swizzle (handles nwg % 8 != 0)
    const int orig = blockIdx.x - nScat;
    const int q = nwg >> 3, r = nwg & 7;
    const int xcd = orig & 7;
    const int base = (xcd < r) ? xcd * (q + 1) : r * (q + 1) + (xcd - r) * q;
    const int wgid = base + (orig >> 3);
    const int bx = wgid / nby, by = wgid % nby;   // by-fastest: same-bx blocks consecutive

    const int wid  = threadIdx.x >> 6;
    const int lane = threadIdx.x & 63;
    const int wr = wid >> 1, wc = wid & 1;
    const int bm = bx * 128;
    const int bn = by * 128;
    const int lr = lane & 15;
    const int lk = lane >> 4;
    const int srow   = lane >> 3;
    const int schunk = lane & 7;

    f32x4 acc[4][4];
#pragma unroll
    for (int m = 0; m < 4; ++m)
#pragma unroll
        for (int n = 0; n < 4; ++n) acc[m][n] = (f32x4){0.f, 0.f, 0.f, 0.f};

    // prologue: stage slab 0 into buffer 0
#pragma unroll
    for (int i = 0; i < 4; ++i) {
        int seg = wid * 4 + i;
        int row = seg * 8 + srow;
        gl2lds16(A + (size_t)(bm + row) * K + schunk * 8, As[0] + seg * 512);
        gl2lds16(W + (size_t)(bn + row) * K + schunk * 8, Bs[0] + seg * 512);
    }
    __syncthreads();   // compiler emits vmcnt(0) drain: slab 0 resident

    int cur = 0;
    for (int k0 = 0; k0 < K; k0 += 64) {
        const int kn = k0 + 64;
        if (kn < K) {   // stage next slab into the other buffer (overlaps MFMA below)
#pragma unroll
            for (int i = 0; i < 4; ++i) {
                int seg = wid * 4 + i;
                int row = seg * 8 + srow;
                gl2lds16(A + (size_t)(bm + row) * K + kn + schunk * 8, As[cur ^ 1] + seg * 512);
                gl2lds16(W + (size_t)(bn + row) * K + kn + schunk * 8, Bs[cur ^ 1] + seg * 512);
            }
        }

#pragma unroll
        for (int ks = 0; ks < 2; ++ks) {
            bf16x8 a[4], b[4];
#pragma unroll
            for (int m = 0; m < 4; ++m)
                a[m] = *(const bf16x8*)(As[cur] + (wr * 64 + m * 16 + lr) * 64 + ks * 32 + lk * 8);
#pragma unroll
            for (int n = 0; n < 4; ++n)
                b[n] = *(const bf16x8*)(Bs[cur] + (wc * 64 + n * 16 + lr) * 64 + ks * 32 + lk * 8);
#pragma unroll
            for (int m = 0; m < 4; ++m)
#pragma unroll
                for (int n = 0; n < 4; ++n)
                    acc[m][n] = __builtin_amdgcn_mfma_f32_16x16x32_bf16(a[m], b[n], acc[m][n], 0, 0, 0);
        }
        __syncthreads();   // drains this step's stage (vmcnt(0)) + WAR-protects As[cur]
        cur ^= 1;
    }

    const bool isP = (bn + wc * 64) < PC;  // wave-uniform (PC multiple of 64)
#pragma unroll
    for (int m = 0; m < 4; ++m)
#pragma unroll
        for (int r2 = 0; r2 < 4; ++r2) {
            int row = bm + wr * 64 + m * 16 + lk * 4 + r2;
            if (row < N) {
                if (isP) {
#pragma unroll
                    for (int n = 0; n < 4; ++n) {
                        int col = bn + wc * 64 + n * 16 + lr;
                        Cp[(size_t)row * PC + col] = f2fp8(acc[m][n][r2]);
                    }
                } else {
#pragma unroll
                    for (int n = 0; n < 4; ++n) {
                        int col = bn + wc * 64 + n * 16 + lr - PC;
                        Cr[(size_t)row * PC + col] = f2b(acc[m][n][r2]);
                    }
                }
            }
        }
}

// ---------------- fused aggregate, edge-slot-parallel, 4-edge unroll, fp8 gather ----------------
// Layer 1: P1 [N,256] fp8, R1 [N,256] bf16 -> h [N,256] bf16.

__global__ __launch_bounds__(256) void k_agg1(const unsigned char* __restrict__ P1,
                                              const ushort* __restrict__ R1,
                                              const float* __restrict__ bias,
                                              const int* __restrict__ row_start,
                                              const int* __restrict__ eidx,
                                              ushort* __restrict__ h, int N) {
    int node = (blockIdx.x * blockDim.x + threadIdx.x) >> 6;
    int lane = threadIdx.x & 63;
    if (node >= N) return;
    const int slot = lane >> 4;   // 0..3
    const int sub  = lane & 15;   // 16 channels each
    int s0 = row_start[node], s1 = row_start[node + 1];

    float acc[16];
#pragma unroll
    for (int i = 0; i < 16; ++i) acc[i] = 0.f;

    for (int e = s0 + slot; e < s1; e += 16) {
        int e1 = e + 4, e2 = e + 8, e3 = e + 12;
        bool h1 = e1 < s1, h2 = e2 < s1, h3 = e3 < s1;
        int sA = eidx[e];
        int sB = h1 ? eidx[e1] : sA;
        int sC = h2 ? eidx[e2] : sA;
        int sD = h3 ? eidx[e3] : sA;
        u32x4 a = *(const u32x4*)(P1 + (size_t)sA * 256 + sub * 16);
        u32x4 b = *(const u32x4*)(P1 + (size_t)sB * 256 + sub * 16);
        u32x4 c = *(const u32x4*)(P1 + (size_t)sC * 256 + sub * 16);
        u32x4 d = *(const u32x4*)(P1 + (size_t)sD * 256 + sub * 16);
#pragma unroll
        for (int w = 0; w < 4; ++w) fp8acc4(a[w], acc[w*4], acc[w*4+1], acc[w*4+2], acc[w*4+3]);
        if (h1) {
#pragma unroll
            for (int w = 0; w < 4; ++w) fp8acc4(b[w], acc[w*4], acc[w*4+1], acc[w*4+2], acc[w*4+3]);
        }
        if (h2) {
#pragma unroll
            for (int w = 0; w < 4; ++w) fp8acc4(c[w], acc[w*4], acc[w*4+1], acc[w*4+2], acc[w*4+3]);
        }
        if (h3) {
#pragma unroll
            for (int w = 0; w < 4; ++w) fp8acc4(d[w], acc[w*4], acc[w*4+1], acc[w*4+2], acc[w*4+3]);
        }
    }

#pragma unroll
    for (int i = 0; i < 16; ++i) {
        acc[i] += __shfl_xor(acc[i], 16, 64);
        acc[i] += __shfl_xor(acc[i], 32, 64);
    }

    if (slot == 0) {
        int d = s1 - s0;
        float inv = 1.0f / (float)(d > 1 ? d : 1);
        const ushort* rp = R1 + (size_t)node * 256 + sub * 16;
        ushortx8 r0 = *(const ushortx8*)(rp);
        ushortx8 r1 = *(const ushortx8*)(rp + 8);
        const float* bp = bias + sub * 16;
        ushortx8 o0, o1;
#pragma unroll
        for (int i = 0; i < 8; ++i) {
            float v0 = fmaxf(acc[i] * inv + bp[i] + b2f(r0[i]), 0.f);
            float v1 = fmaxf(acc[i + 8] * inv + bp[i + 8] + b2f(r1[i]), 0.f);
            o0[i] = f2b(v0);
            o1[i] = f2b(v1);
        }
        ushort* hp = h + (size_t)node * 256 + sub * 16;
        *(ushortx8*)(hp) = o0;
        *(ushortx8*)(hp + 8) = o1;
    }
}

// Layer 2: P2 [N,64] fp8, R2 [N,64] bf16 -> out [N,64] f32.

__global__ __launch_bounds__(256) void k_agg2(const unsigned char* __restrict__ P2,
                                              const ushort* __restrict__ R2,
                                              const float* __restrict__ bias,
                                              const int* __restrict__ row_start,
                                              const int* __restrict__ eidx,
                                              float* __restrict__ out, int N) {
    int node = (blockIdx.x * blockDim.x + threadIdx.x) >> 6;
    int lane = threadIdx.x & 63;
    if (node >= N) return;
    const int slot = lane >> 3;   // 0..7
    const int sub  = lane & 7;    // 8 channels each
    int s0 = row_start[node], s1 = row_start[node + 1];

    float acc[8];
#pragma unroll
    for (int i = 0; i < 8; ++i) acc[i] = 0.f;

    for (int e = s0 + slot; e < s1; e += 32) {
        int e1 = e + 8, e2 = e + 16, e3 = e + 24;
        bool h1 = e1 < s1, h2 = e2 < s1, h3 = e3 < s1;
        int sA = eidx[e];
        int sB = h1 ? eidx[e1] : sA;
        int sC = h2 ? eidx[e2] : sA;
        int sD = h3 ? eidx[e3] : sA;
        u32x2 a = *(const u32x2*)(P2 + (size_t)sA * 64 + sub * 8);
        u32x2 b = *(const u32x2*)(P2 + (size_t)sB * 64 + sub * 8);
        u32x2 c = *(const u32x2*)(P2 + (size_t)sC * 64 + sub * 8);
        u32x2 d = *(const u32x2*)(P2 + (size_t)sD * 64 + sub * 8);
#pragma unroll
        for (int w = 0; w < 2; ++w) fp8acc4(a[w], acc[w*4], acc[w*4+1], acc[w*4+2], acc[w*4+3]);
        if (h1) {
#pragma unroll
            for (int w = 0; w < 2; ++w) fp8acc4(b[w], acc[w*4], acc[w*4+1], acc[w*4+2], acc[w*4+3]);
        }
        if (h2) {
#pragma unroll
            for (int w = 0; w < 2; ++w) fp8acc4(c[w], acc[w*4], acc[w*4+1], acc[w*4+2], acc[w*4+3]);
        }
        if (h3) {
#pragma unroll
            for (int w = 0; w < 2; ++w) fp8acc4(d[w], acc[w*4], acc[w*4+1], acc[w*4+2], acc[w*4+3]);
        }
    }

#pragma unroll
    for (int i = 0; i < 8; ++i) {
        acc[i] += __shfl_xor(acc[i], 8, 64);
        acc[i] += __shfl_xor(acc[i], 16, 64);
        acc[i] += __shfl_xor(acc[i], 32, 64);
    }

    if (slot == 0) {
        int d = s1 - s0;
        float inv = 1.0f / (float)(d > 1 ? d : 1);
        ushortx8 rv = *(const ushortx8*)(R2 + (size_t)node * 64 + sub * 8);
        const float* bp = bias + sub * 8;
        float o[8];
#pragma unroll
        for (int i = 0; i < 8; ++i) o[i] = acc[i] * inv + bp[i] + b2f(rv[i]);
        float4* op = (float4*)(out + (size_t)node * 64 + sub * 8);
        op[0] = make_float4(o[0], o[1], o[2], o[3]);
        op[1] = make_float4(o[4], o[5], o[6], o[7]);
    }
}

// ---------------- launch ----------------

extern "C" void kernel_launch(void* const* d_in, const int* in_sizes, int n_in,
                              void* d_out, int out_size, void* d_ws, size_t ws_size,
                              hipStream_t stream) {
    const float* x    = (const float*)d_in[0];
    const float* W_l1 = (const float*)d_in[1];
    const float* b1   = (const float*)d_in[2];
    const float* W_r1 = (const float*)d_in[3];
    const float* W_l2 = (const float*)d_in[4];
    const float* b2   = (const float*)d_in[5];
    const float* W_r2 = (const float*)d_in[6];
    const int*   ei   = (const int*)d_in[7];

    const int N = in_sizes[0] / IN_C;
    const int E = in_sizes[7] / 2;
    const int EPB = (E + NBK - 1) / NBK;  // 12500 < 65536 (rank fits u16)
    const int* src = ei;
    const int* dst = ei + E;

    char* ws = (char*)d_ws;
    size_t off_ = 0;
    auto alloc = [&](size_t bytes) -> void* {
        void* p = ws + off_;
        off_ += (bytes + 255) & ~(size_t)255;
        return p;
    };
    unsigned int*  cnt32     = (unsigned int*)alloc((size_t)NBK * N2 * 4);   // cnt16[b][n]
    ushort*        off16     = (ushort*)alloc((size_t)NBK * NPAD * 2);       // off16[b][n]
    int*           chunkpart = (int*)alloc((size_t)NCH * NBK * 4);
    int*           row_start = (int*)alloc((size_t)(N + 1) * 4);
    ushort*        rank      = (ushort*)alloc((size_t)E * 2);
    int*           eidx      = (int*)alloc((size_t)E * 4);
    ushort*        xb        = (ushort*)alloc((size_t)N * IN_C * 2);
    ushort*        Wc1       = (ushort*)alloc((size_t)2 * HID_C * IN_C * 2);   // [512,256]
    ushort*        Wc2       = (ushort*)alloc((size_t)2 * OUT_C * HID_C * 2);  // [128,256]
    unsigned char* P1        = (unsigned char*)alloc((size_t)N * HID_C);      // [N,256] fp8
    ushort*        R1        = (ushort*)alloc((size_t)N * HID_C * 2);         // [N,256] bf16
    ushort*        h         = (ushort*)alloc((size_t)N * HID_C * 2);         // [N,256] bf16
    unsigned char* P2        = (unsigned char*)alloc((size_t)N * OUT_C);      // [N,64] fp8
    ushort*        R2        = (ushort*)alloc((size_t)N * OUT_C * 2);         // [N,64] bf16
    (void)alloc(128 * 512 * 2);  // tail pad: last M-block OOB staging reads land here
    (void)ws_size; (void)n_in; (void)out_size;

    // ---- K1: LDS-hist degree/rank (disjoint slices, zero global atomics) || conversions ----
    {
        int xUnits = N * IN_C / 8;
        k_front<<<NBK + 256, 1024, 0, stream>>>(dst, E, EPB, rank, cnt32, chunkpart,
                                                x, xb, xUnits,
                                                W_l1, W_r1, W_l2, W_r2, Wc1, Wc2);
    }

    // ---- K2: CSR scan (row_start + per-slice offsets) ----
    k_scan<<<NCH, 256, 0, stream>>>(cnt32, chunkpart, N, row_start, off16);

    // ---- layer 1: [atomic-free scatter || P1,R1 = xb @ Wc1^T]; h = relu(agg(P1)/deg + b1 + R1) ----
    {
        // R17 change 2: nScat 128 -> 448. The scatter tail previously ran at
        // ~2 waves/CU on a 2-level dependent random-load chain and set the
        // dispatch duration; 448 blocks (~7 edges/thread) finish inside the
        // GEMM phase.
        const int nScat = 448;
        int nbx = (N + 127) / 128, nby = (2 * HID_C) / 128;
        int nwg = nbx * nby;   // 391*4 = 1564 (NOT a multiple of 8)
        k_gemm_mfma<<<nScat + nwg, 256, 0, stream>>>(xb, Wc1, P1, R1, N, IN_C, HID_C, nby, nwg,
                                                     nScat, src, dst, rank, row_start, off16,
                                                     E, EPB, eidx);
        k_agg1<<<(N + 3) / 4, 256, 0, stream>>>(P1, R1, b1, row_start, eidx, h, N);
    }

    // ---- layer 2: P2,R2 = h @ Wc2^T; out = agg(P2)/deg + b2 + R2 ----
    {
        int nbx = (N + 127) / 128, nby = (2 * OUT_C) / 128;
        int nwg = nbx * nby;   // 391 (NOT a multiple of 8)
        k_gemm_mfma<<<nwg, 256, 0, stream>>>(h, Wc2, P2, R2, N, HID_C, OUT_C, nby, nwg,
                                             0, nullptr, nullptr, nullptr, nullptr, nullptr,
                                             0, 0, nullptr);
        k_agg2<<<(N + 3) / 4, 256, 0, stream>>>(P2, R2, b2, row_start, eidx, (float*)d_out, N);
    }
}

// Round 2
// 147.677 us; speedup vs baseline: 1.0291x; 1.0291x over previous
//
#include <hip/hip_runtime.h>

#define IN_C 256
#define HID_C 256
#define OUT_C 64

#define NBK 64           // edge slices (= hist blocks)
#define NPAD 50176       // nodes padded to 196*256
#define N2 (NPAD / 2)    // packed u32 histogram entries (25088 -> 100352 B LDS)
#define NCH (NPAD / 256) // 196 chunks

typedef __attribute__((ext_vector_type(8))) short bf16x8;
typedef __attribute__((ext_vector_type(4))) float f32x4;
typedef __attribute__((ext_vector_type(2))) float f32x2;
typedef __attribute__((ext_vector_type(8))) unsigned short ushortx8;
typedef __attribute__((ext_vector_type(4))) unsigned int u32x4;
typedef __attribute__((ext_vector_type(2))) unsigned int u32x2;

__device__ inline float b2f(unsigned short u) {
    union { unsigned int u; float f; } v; v.u = ((unsigned int)u) << 16; return v.f;
}
__device__ inline unsigned short f2b(float f) {
    union { float f; unsigned int u; } v; v.f = f;
    unsigned int u = v.u;
    unsigned int r = (u + 0x7fffu + ((u >> 16) & 1u)) >> 16;  // RNE, no NaN expected
    return (unsigned short)r;
}

// fp8 (OCP e4m3) encode/decode via gfx950 HW converts
__device__ __forceinline__ unsigned char f2fp8(float v) {
    int pk = __builtin_amdgcn_cvt_pk_fp8_f32(v, v, 0, false);
    return (unsigned char)(pk & 0xff);
}
__device__ __forceinline__ void fp8acc4(unsigned int w, float& a0, float& a1, float& a2, float& a3) {
    f32x2 lo = __builtin_amdgcn_cvt_pk_f32_fp8((int)w, false);
    f32x2 hi = __builtin_amdgcn_cvt_pk_f32_fp8((int)w, true);
    a0 += lo.x; a1 += lo.y; a2 += hi.x; a3 += hi.y;
}

__device__ __forceinline__ void gl2lds16(const ushort* g, ushort* l) {
    __builtin_amdgcn_global_load_lds((const __attribute__((address_space(1))) void*)g,
                                     (__attribute__((address_space(3))) void*)l, 16, 0, 0);
}

__device__ __forceinline__ void conv8(const float* __restrict__ src, ushort* __restrict__ dst, int u) {
    const float4* p = (const float4*)(src + (size_t)u * 8);
    float4 a = p[0], b = p[1];
    ushort4 o0 = make_ushort4(f2b(a.x), f2b(a.y), f2b(a.z), f2b(a.w));
    ushort4 o1 = make_ushort4(f2b(b.x), f2b(b.y), f2b(b.z), f2b(b.w));
    ((ushort4*)(dst + (size_t)u * 8))[0] = o0;
    ((ushort4*)(dst + (size_t)u * 8))[1] = o1;
}

// ---------------- K1: full-N LDS-histogram degree+rank (disjoint slices) || conversions --------

__global__ __launch_bounds__(1024) void k_front(const int* __restrict__ dst, int E, int EPB,
                                                ushort* __restrict__ rank,
                                                unsigned int* __restrict__ cnt32,
                                                int* __restrict__ chunkpart,
                                                const float* __restrict__ x, ushort* __restrict__ xb,
                                                int xUnits,
                                                const float* __restrict__ Wl1, const float* __restrict__ Wr1,
                                                const float* __restrict__ Wl2, const float* __restrict__ Wr2,
                                                ushort* __restrict__ Wc1, ushort* __restrict__ Wc2) {
    const int bid = blockIdx.x;
    const int t = threadIdx.x;

    if (bid < NBK) {
        __shared__ unsigned int h[N2];  // 100352 B
        for (int i = t; i < N2; i += 1024) h[i] = 0;
        __syncthreads();

        const int e0 = bid * EPB;
        const int e1 = min(e0 + EPB, E);
        for (int e = e0 + t; e < e1; e += 1024) {
            int d = dst[e];
            int sh = (d & 1) << 4;
            unsigned int old = atomicAdd(&h[d >> 1], 1u << sh);
            rank[e] = (ushort)((old >> sh) & 0xffffu);
        }
        __syncthreads();

        unsigned int* outp = cnt32 + (size_t)bid * N2;
        for (int i = t; i < N2; i += 1024) outp[i] = h[i];

        if (t < NCH) {
            int c = t;
            int sum = 0;
#pragma unroll 8
            for (int j = 0; j < 128; ++j) {
                unsigned int v = h[c * 128 + ((j + c) & 127)];
                sum += (int)(v & 0xffffu) + (int)(v >> 16);
            }
            chunkpart[c * NBK + bid] = sum;
        }
        return;
    }

    const int ct = (bid - NBK) * 1024 + t;
    const int cn = 256 * 1024;
    for (int i = ct; i < 20480; i += cn) {
        if (i < 8192)       conv8(Wl1, Wc1,         i);
        else if (i < 16384) conv8(Wr1, Wc1 + 65536, i - 8192);
        else if (i < 18432) conv8(Wl2, Wc2,         i - 16384);
        else                conv8(Wr2, Wc2 + 16384, i - 18432);
    }
    for (int u = ct; u < xUnits; u += cn) conv8(x, xb, u);
}

// ---------------- K2: CSR scan; emits row_start + per-node per-slice offsets off16 ----------

__global__ __launch_bounds__(256) void k_scan(const unsigned int* __restrict__ cnt32,
                                              const int* __restrict__ chunkpart, int N,
                                              int* __restrict__ row_start,
                                              ushort* __restrict__ off16) {
    __shared__ int s[256];
    const int bid = blockIdx.x;
    const int t = threadIdx.x;

    int pre = 0;
    const int limit = bid * NBK;
    for (int i = t; i < limit; i += 256) pre += chunkpart[i];
    s[t] = pre;
    __syncthreads();
    for (int o = 128; o > 0; o >>= 1) {
        if (t < o) s[t] += s[t + o];
        __syncthreads();
    }
    const int chunk_off = s[0];
    __syncthreads();

    const int i = bid * 256 + t;
    const ushort* cnt16 = (const ushort*)cnt32;
    int run = 0;
#pragma unroll 8
    for (int b = 0; b < NBK; ++b) {
        ushort cv = cnt16[(size_t)b * NPAD + i];
        off16[(size_t)b * NPAD + i] = (ushort)run;
        run += cv;
    }
    int deg = run;

    s[t] = deg;
    __syncthreads();
    for (int o = 1; o < 256; o <<= 1) {
        int xx = (t >= o) ? s[t - o] : 0;
        __syncthreads();
        s[t] += xx;
        __syncthreads();
    }
    if (i < N) row_start[i + 1] = s[t] + chunk_off;
    if (i == 0) row_start[0] = 0;
}

// ---------------- R18: layer-1 GEMM, A-resident per block + W-streamed ----------------
// BM=64: block stages its 64x256 A-tile ONCE (32KB LDS, full K), then streams all
// four 128-col W-slabs (16KB each, dbuf 2x16KB) through a rolling 16-step pipeline,
// producing the full 64x512 output panel. Kills the 4x A re-staging (nby=4 -> 1).
// T2 both-sides XOR swizzle (rule 21): LDS dest stays LINEAR (gl2lds requirement),
// global SOURCE chunk pre-swizzled with chunk ^= (row&7), ds_read applies the same
// XOR -> 16-way bank conflict (4.8M cycles measured) -> ~2-way (free).
// LDS 64KB -> 2 blocks/CU. Fused atomic-free scatter unchanged (nScat blocks).

__global__ __launch_bounds__(256) void k_gemm_l1(const ushort* __restrict__ A,
                                                 const ushort* __restrict__ W,
                                                 unsigned char* __restrict__ Cp,
                                                 ushort* __restrict__ Cr,
                                                 int N, int nScat,
                                                 const int* __restrict__ src, const int* __restrict__ dst,
                                                 const ushort* __restrict__ rank,
                                                 const int* __restrict__ row_start,
                                                 const ushort* __restrict__ off16,
                                                 int E, int EPB, int* __restrict__ eidx) {
    if (blockIdx.x < (unsigned)nScat) {
        int base = blockIdx.x * 256 + threadIdx.x;
        int stride = nScat * 256;
        for (int e = base; e < E; e += stride) {
            int d = dst[e];
            int b = e / EPB;
            eidx[row_start[d] + (int)off16[(size_t)b * NPAD + d] + (int)rank[e]] = src[e];
        }
        return;
    }

    __shared__ ushort Aall[64 * 256];      // 32KB, full-K A tile (linear, source-swizzled)
    __shared__ ushort Wb[2 * 128 * 64];    // 2x16KB W slab double-buffer

    const int bx = blockIdx.x - nScat;
    const int t = threadIdx.x;
    const int bm = bx * 64;

    const int wid  = t >> 6;
    const int lane = t & 63;
    const int wr = wid >> 1;          // 0..1: row half (32 rows)
    const int wc = wid & 1;           // 0..1: col half within 128-col slab (64 cols)
    const int lr = lane & 15;
    const int lk = lane >> 4;

    // ---- prologue: stage full A tile (8 passes) + W slab 0 ----
    {
        const int arow7 = (t >> 5) & 7;          // row & 7 for A staging lanes
        const int asrc  = ((t & 31) ^ arow7) << 3;  // source chunk pre-swizzle
#pragma unroll
        for (int i = 0; i < 8; ++i) {
            gl2lds16(A + (size_t)(bm + i * 8 + (t >> 5)) * 256 + asrc,
                     Aall + i * 2048 + t * 8);
        }
        const int wrow7 = (t >> 3) & 7;
        const int wsrc  = ((t & 7) ^ wrow7) << 3;
#pragma unroll
        for (int i = 0; i < 4; ++i) {
            gl2lds16(W + (size_t)(i * 32 + (t >> 3)) * 256 + 0 + wsrc,
                     Wb + i * 2048 + t * 8);
        }
    }
    __syncthreads();

    f32x4 acc[2][4];
    int s = 0;
#pragma unroll
    for (int by = 0; by < 4; ++by) {
#pragma unroll
        for (int m = 0; m < 2; ++m)
#pragma unroll
            for (int n = 0; n < 4; ++n) acc[m][n] = (f32x4){0.f, 0.f, 0.f, 0.f};

#pragma unroll
        for (int kk = 0; kk < 4; ++kk, ++s) {
            const int sn = s + 1;
            if (sn < 16) {  // stage next W slab into the other buffer
                const int by_n = sn >> 2, kk_n = sn & 3, buf_n = sn & 1;
                const int wrow7 = (t >> 3) & 7;
                const int wsrc  = ((t & 7) ^ wrow7) << 3;
#pragma unroll
                for (int i = 0; i < 4; ++i) {
                    gl2lds16(W + (size_t)(by_n * 128 + i * 32 + (t >> 3)) * 256 + kk_n * 64 + wsrc,
                             Wb + buf_n * 8192 + i * 2048 + t * 8);
                }
            }

            // compute step s: A k-range [kk*64, kk*64+64), W slab in Wb[s&1]
            const int kb = kk * 8;           // 16B-chunk base within A row
            const int buf = s & 1;
            const int sw = lr & 7;           // read-side XOR
#pragma unroll
            for (int ks = 0; ks < 2; ++ks) {
                bf16x8 a[2], b[4];
                const int ck = ks * 4 + lk;  // logical chunk within 64-k slab
#pragma unroll
                for (int m = 0; m < 2; ++m)
                    a[m] = *(const bf16x8*)(Aall + (wr * 32 + m * 16 + lr) * 256 + ((kb + (ck ^ sw)) << 3));
#pragma unroll
                for (int n = 0; n < 4; ++n)
                    b[n] = *(const bf16x8*)(Wb + buf * 8192 + (wc * 64 + n * 16 + lr) * 64 + ((ck ^ sw) << 3));
#pragma unroll
                for (int m = 0; m < 2; ++m)
#pragma unroll
                    for (int n = 0; n < 4; ++n)
                        acc[m][n] = __builtin_amdgcn_mfma_f32_16x16x32_bf16(a[m], b[n], acc[m][n], 0, 0, 0);
            }

            if (kk == 3) {  // epilogue for this by-slab (overlaps the already-issued next stage)
                const bool isP = (by * 128 + wc * 64) < HID_C;  // wave-uniform
#pragma unroll
                for (int m = 0; m < 2; ++m)
#pragma unroll
                    for (int r2 = 0; r2 < 4; ++r2) {
                        int row = bm + wr * 32 + m * 16 + lk * 4 + r2;
                        if (row < N) {
                            if (isP) {
#pragma unroll
                                for (int n = 0; n < 4; ++n) {
                                    int col = by * 128 + wc * 64 + n * 16 + lr;
                                    Cp[(size_t)row * HID_C + col] = f2fp8(acc[m][n][r2]);
                                }
                            } else {
#pragma unroll
                                for (int n = 0; n < 4; ++n) {
                                    int col = by * 128 + wc * 64 + n * 16 + lr - HID_C;
                                    Cr[(size_t)row * HID_C + col] = f2b(acc[m][n][r2]);
                                }
                            }
                        }
                    }
            }
            __syncthreads();   // drains next-slab stage (vmcnt0) + WAR on Wb[buf]
        }
    }
}

// ---------------- layer-2 GEMM (R14-verified body, unchanged) --------

__global__ __launch_bounds__(256) void k_gemm_mfma(const ushort* __restrict__ A,
                                                   const ushort* __restrict__ W,
                                                   unsigned char* __restrict__ Cp,
                                                   ushort* __restrict__ Cr,
                                                   int N, int K, int PC, int nby, int nwg) {
    __shared__ ushort As[2][128 * 64];
    __shared__ ushort Bs[2][128 * 64];

    const int orig = blockIdx.x;
    const int q = nwg >> 3, r = nwg & 7;
    const int xcd = orig & 7;
    const int base = (xcd < r) ? xcd * (q + 1) : r * (q + 1) + (xcd - r) * q;
    const int wgid = base + (orig >> 3);
    const int bx = wgid / nby, by = wgid % nby;

    const int wid  = threadIdx.x >> 6;
    const int lane = threadIdx.x & 63;
    const int wr = wid >> 1, wc = wid & 1;
    const int bm = bx * 128;
    const int bn = by * 128;
    const int lr = lane & 15;
    const int lk = lane >> 4;
    const int srow   = lane >> 3;
    const int schunk = lane & 7;

    f32x4 acc[4][4];
#pragma unroll
    for (int m = 0; m < 4; ++m)
#pragma unroll
        for (int n = 0; n < 4; ++n) acc[m][n] = (f32x4){0.f, 0.f, 0.f, 0.f};

#pragma unroll
    for (int i = 0; i < 4; ++i) {
        int seg = wid * 4 + i;
        int row = seg * 8 + srow;
        gl2lds16(A + (size_t)(bm + row) * K + schunk * 8, As[0] + seg * 512);
        gl2lds16(W + (size_t)(bn + row) * K + schunk * 8, Bs[0] + seg * 512);
    }
    __syncthreads();

    int cur = 0;
    for (int k0 = 0; k0 < K; k0 += 64) {
        const int kn = k0 + 64;
        if (kn < K) {
#pragma unroll
            for (int i = 0; i < 4; ++i) {
                int seg = wid * 4 + i;
                int row = seg * 8 + srow;
                gl2lds16(A + (size_t)(bm + row) * K + kn + schunk * 8, As[cur ^ 1] + seg * 512);
                gl2lds16(W + (size_t)(bn + row) * K + kn + schunk * 8, Bs[cur ^ 1] + seg * 512);
            }
        }

#pragma unroll
        for (int ks = 0; ks < 2; ++ks) {
            bf16x8 a[4], b[4];
#pragma unroll
            for (int m = 0; m < 4; ++m)
                a[m] = *(const bf16x8*)(As[cur] + (wr * 64 + m * 16 + lr) * 64 + ks * 32 + lk * 8);
#pragma unroll
            for (int n = 0; n < 4; ++n)
                b[n] = *(const bf16x8*)(Bs[cur] + (wc * 64 + n * 16 + lr) * 64 + ks * 32 + lk * 8);
#pragma unroll
            for (int m = 0; m < 4; ++m)
#pragma unroll
                for (int n = 0; n < 4; ++n)
                    acc[m][n] = __builtin_amdgcn_mfma_f32_16x16x32_bf16(a[m], b[n], acc[m][n], 0, 0, 0);
        }
        __syncthreads();
        cur ^= 1;
    }

    const bool isP = (bn + wc * 64) < PC;
#pragma unroll
    for (int m = 0; m < 4; ++m)
#pragma unroll
        for (int r2 = 0; r2 < 4; ++r2) {
            int row = bm + wr * 64 + m * 16 + lk * 4 + r2;
            if (row < N) {
                if (isP) {
#pragma unroll
                    for (int n = 0; n < 4; ++n) {
                        int col = bn + wc * 64 + n * 16 + lr;
                        Cp[(size_t)row * PC + col] = f2fp8(acc[m][n][r2]);
                    }
                } else {
#pragma unroll
                    for (int n = 0; n < 4; ++n) {
                        int col = bn + wc * 64 + n * 16 + lr - PC;
                        Cr[(size_t)row * PC + col] = f2b(acc[m][n][r2]);
                    }
                }
            }
        }
}

// ---------------- fused aggregate, edge-slot-parallel, 4-edge unroll, fp8 gather ----------------
// Layer 1: P1 [N,256] fp8, R1 [N,256] bf16 -> h [N,256] bf16.

__global__ __launch_bounds__(256) void k_agg1(const unsigned char* __restrict__ P1,
                                              const ushort* __restrict__ R1,
                                              const float* __restrict__ bias,
                                              const int* __restrict__ row_start,
                                              const int* __restrict__ eidx,
                                              ushort* __restrict__ h, int N) {
    int node = (blockIdx.x * blockDim.x + threadIdx.x) >> 6;
    int lane = threadIdx.x & 63;
    if (node >= N) return;
    const int slot = lane >> 4;   // 0..3
    const int sub  = lane & 15;   // 16 channels each
    int s0 = row_start[node], s1 = row_start[node + 1];

    float acc[16];
#pragma unroll
    for (int i = 0; i < 16; ++i) acc[i] = 0.f;

    for (int e = s0 + slot; e < s1; e += 16) {
        int e1 = e + 4, e2 = e + 8, e3 = e + 12;
        bool h1 = e1 < s1, h2 = e2 < s1, h3 = e3 < s1;
        int sA = eidx[e];
        int sB = h1 ? eidx[e1] : sA;
        int sC = h2 ? eidx[e2] : sA;
        int sD = h3 ? eidx[e3] : sA;
        u32x4 a = *(const u32x4*)(P1 + (size_t)sA * 256 + sub * 16);
        u32x4 b = *(const u32x4*)(P1 + (size_t)sB * 256 + sub * 16);
        u32x4 c = *(const u32x4*)(P1 + (size_t)sC * 256 + sub * 16);
        u32x4 d = *(const u32x4*)(P1 + (size_t)sD * 256 + sub * 16);
#pragma unroll
        for (int w = 0; w < 4; ++w) fp8acc4(a[w], acc[w*4], acc[w*4+1], acc[w*4+2], acc[w*4+3]);
        if (h1) {
#pragma unroll
            for (int w = 0; w < 4; ++w) fp8acc4(b[w], acc[w*4], acc[w*4+1], acc[w*4+2], acc[w*4+3]);
        }
        if (h2) {
#pragma unroll
            for (int w = 0; w < 4; ++w) fp8acc4(c[w], acc[w*4], acc[w*4+1], acc[w*4+2], acc[w*4+3]);
        }
        if (h3) {
#pragma unroll
            for (int w = 0; w < 4; ++w) fp8acc4(d[w], acc[w*4], acc[w*4+1], acc[w*4+2], acc[w*4+3]);
        }
    }

#pragma unroll
    for (int i = 0; i < 16; ++i) {
        acc[i] += __shfl_xor(acc[i], 16, 64);
        acc[i] += __shfl_xor(acc[i], 32, 64);
    }

    if (slot == 0) {
        int d = s1 - s0;
        float inv = 1.0f / (float)(d > 1 ? d : 1);
        const ushort* rp = R1 + (size_t)node * 256 + sub * 16;
        ushortx8 r0 = *(const ushortx8*)(rp);
        ushortx8 r1 = *(const ushortx8*)(rp + 8);
        const float* bp = bias + sub * 16;
        ushortx8 o0, o1;
#pragma unroll
        for (int i = 0; i < 8; ++i) {
            float v0 = fmaxf(acc[i] * inv + bp[i] + b2f(r0[i]), 0.f);
            float v1 = fmaxf(acc[i + 8] * inv + bp[i + 8] + b2f(r1[i]), 0.f);
            o0[i] = f2b(v0);
            o1[i] = f2b(v1);
        }
        ushort* hp = h + (size_t)node * 256 + sub * 16;
        *(ushortx8*)(hp) = o0;
        *(ushortx8*)(hp + 8) = o1;
    }
}

// Layer 2: P2 [N,64] fp8, R2 [N,64] bf16 -> out [N,64] f32.

__global__ __launch_bounds__(256) void k_agg2(const unsigned char* __restrict__ P2,
                                              const ushort* __restrict__ R2,
                                              const float* __restrict__ bias,
                                              const int* __restrict__ row_start,
                                              const int* __restrict__ eidx,
                                              float* __restrict__ out, int N) {
    int node = (blockIdx.x * blockDim.x + threadIdx.x) >> 6;
    int lane = threadIdx.x & 63;
    if (node >= N) return;
    const int slot = lane >> 3;   // 0..7
    const int sub  = lane & 7;    // 8 channels each
    int s0 = row_start[node], s1 = row_start[node + 1];

    float acc[8];
#pragma unroll
    for (int i = 0; i < 8; ++i) acc[i] = 0.f;

    for (int e = s0 + slot; e < s1; e += 32) {
        int e1 = e + 8, e2 = e + 16, e3 = e + 24;
        bool h1 = e1 < s1, h2 = e2 < s1, h3 = e3 < s1;
        int sA = eidx[e];
        int sB = h1 ? eidx[e1] : sA;
        int sC = h2 ? eidx[e2] : sA;
        int sD = h3 ? eidx[e3] : sA;
        u32x2 a = *(const u32x2*)(P2 + (size_t)sA * 64 + sub * 8);
        u32x2 b = *(const u32x2*)(P2 + (size_t)sB * 64 + sub * 8);
        u32x2 c = *(const u32x2*)(P2 + (size_t)sC * 64 + sub * 8);
        u32x2 d = *(const u32x2*)(P2 + (size_t)sD * 64 + sub * 8);
#pragma unroll
        for (int w = 0; w < 2; ++w) fp8acc4(a[w], acc[w*4], acc[w*4+1], acc[w*4+2], acc[w*4+3]);
        if (h1) {
#pragma unroll
            for (int w = 0; w < 2; ++w) fp8acc4(b[w], acc[w*4], acc[w*4+1], acc[w*4+2], acc[w*4+3]);
        }
        if (h2) {
#pragma unroll
            for (int w = 0; w < 2; ++w) fp8acc4(c[w], acc[w*4], acc[w*4+1], acc[w*4+2], acc[w*4+3]);
        }
        if (h3) {
#pragma unroll
            for (int w = 0; w < 2; ++w) fp8acc4(d[w], acc[w*4], acc[w*4+1], acc[w*4+2], acc[w*4+3]);
        }
    }

#pragma unroll
    for (int i = 0; i < 8; ++i) {
        acc[i] += __shfl_xor(acc[i], 8, 64);
        acc[i] += __shfl_xor(acc[i], 16, 64);
        acc[i] += __shfl_xor(acc[i], 32, 64);
    }

    if (slot == 0) {
        int d = s1 - s0;
        float inv = 1.0f / (float)(d > 1 ? d : 1);
        ushortx8 rv = *(const ushortx8*)(R2 + (size_t)node * 64 + sub * 8);
        const float* bp = bias + sub * 8;
        float o[8];
#pragma unroll
        for (int i = 0; i < 8; ++i) o[i] = acc[i] * inv + bp[i] + b2f(rv[i]);
        float4* op = (float4*)(out + (size_t)node * 64 + sub * 8);
        op[0] = make_float4(o[0], o[1], o[2], o[3]);
        op[1] = make_float4(o[4], o[5], o[6], o[7]);
    }
}

// ---------------- launch ----------------

extern "C" void kernel_launch(void* const* d_in, const int* in_sizes, int n_in,
                              void* d_out, int out_size, void* d_ws, size_t ws_size,
                              hipStream_t stream) {
    const float* x    = (const float*)d_in[0];
    const float* W_l1 = (const float*)d_in[1];
    const float* b1   = (const float*)d_in[2];
    const float* W_r1 = (const float*)d_in[3];
    const float* W_l2 = (const float*)d_in[4];
    const float* b2   = (const float*)d_in[5];
    const float* W_r2 = (const float*)d_in[6];
    const int*   ei   = (const int*)d_in[7];

    const int N = in_sizes[0] / IN_C;
    const int E = in_sizes[7] / 2;
    const int EPB = (E + NBK - 1) / NBK;  // 12500 < 65536 (rank fits u16)
    const int* src = ei;
    const int* dst = ei + E;

    char* ws = (char*)d_ws;
    size_t off_ = 0;
    auto alloc = [&](size_t bytes) -> void* {
        void* p = ws + off_;
        off_ += (bytes + 255) & ~(size_t)255;
        return p;
    };
    unsigned int*  cnt32     = (unsigned int*)alloc((size_t)NBK * N2 * 4);   // cnt16[b][n]
    ushort*        off16     = (ushort*)alloc((size_t)NBK * NPAD * 2);       // off16[b][n]
    int*           chunkpart = (int*)alloc((size_t)NCH * NBK * 4);
    int*           row_start = (int*)alloc((size_t)(N + 1) * 4);
    ushort*        rank      = (ushort*)alloc((size_t)E * 2);
    int*           eidx      = (int*)alloc((size_t)E * 4);
    ushort*        xb        = (ushort*)alloc((size_t)N * IN_C * 2);
    ushort*        Wc1       = (ushort*)alloc((size_t)2 * HID_C * IN_C * 2);   // [512,256]
    ushort*        Wc2       = (ushort*)alloc((size_t)2 * OUT_C * HID_C * 2);  // [128,256]
    unsigned char* P1        = (unsigned char*)alloc((size_t)N * HID_C);      // [N,256] fp8
    ushort*        R1        = (ushort*)alloc((size_t)N * HID_C * 2);         // [N,256] bf16
    ushort*        h         = (ushort*)alloc((size_t)N * HID_C * 2);         // [N,256] bf16
    unsigned char* P2        = (unsigned char*)alloc((size_t)N * OUT_C);      // [N,64] fp8
    ushort*        R2        = (ushort*)alloc((size_t)N * OUT_C * 2);         // [N,64] bf16
    (void)alloc(128 * 512 * 2);  // tail pad: last M-block OOB staging reads land here
    (void)ws_size; (void)n_in; (void)out_size;

    // ---- K1: LDS-hist degree/rank (disjoint slices, zero global atomics) || conversions ----
    {
        int xUnits = N * IN_C / 8;
        k_front<<<NBK + 256, 1024, 0, stream>>>(dst, E, EPB, rank, cnt32, chunkpart,
                                                x, xb, xUnits,
                                                W_l1, W_r1, W_l2, W_r2, Wc1, Wc2);
    }

    // ---- K2: CSR scan (row_start + per-slice offsets) ----
    k_scan<<<NCH, 256, 0, stream>>>(cnt32, chunkpart, N, row_start, off16);

    // ---- layer 1: [atomic-free scatter || P1,R1 = xb @ Wc1^T (A-resident)]; h = agg ----
    {
        const int nScat = 448;
        int nbx = (N + 63) / 64;   // 782 blocks, each produces a 64x512 panel
        k_gemm_l1<<<nScat + nbx, 256, 0, stream>>>(xb, Wc1, P1, R1, N,
                                                   nScat, src, dst, rank, row_start, off16,
                                                   E, EPB, eidx);
        k_agg1<<<(N + 3) / 4, 256, 0, stream>>>(P1, R1, b1, row_start, eidx, h, N);
    }

    // ---- layer 2: P2,R2 = h @ Wc2^T; out = agg(P2)/deg + b2 + R2 ----
    {
        int nbx = (N + 127) / 128, nby = (2 * OUT_C) / 128;
        int nwg = nbx * nby;   // 391
        k_gemm_mfma<<<nwg, 256, 0, stream>>>(h, Wc2, P2, R2, N, HID_C, OUT_C, nby, nwg);
        k_agg2<<<(N + 3) / 4, 256, 0, stream>>>(P2, R2, b2, row_start, eidx, (float*)d_out, N);
    }
}